// Round 7
// baseline (293.106 us; speedup 1.0000x reference)
//
#include <hip/hip_runtime.h>

// Problem: B=32, C=256, H=64, W=64.  Positions = 131072.  269 MB streamed.
//
// History (kernel-only times from rocprof):
//   v2 (8 waves/blk, strided VGPR loads):   99.5 us, total service ~2.7 TB/s
//   v3 (explicit load batches):            124 us   REGRESSION (burst+drain)
//   v4 (16 waves/blk, occ 35->65%):        119 us   no change -> not occupancy
//   v5 (contiguous 256KB chunks, 2-phase): 108 us   no change -> not contiguity
//   v6 (hashed channel-walk rotation):     120 us   no change -> not channel phase
//   v7 (NT vs plain A/B):                  inconclusive (crowded out of top-5 by
//       the harness's 512 MiB ws-poison fills @6.9 TB/s, 77-79 us each)
//
// v8 theory: stores hit 6.9 TB/s (fill), but every VGPR-returning load kernel
//   in the corpus caps at ~2.5-3.2 TB/s read service, while m97's GEMM proves
//   the global_load_lds DMA path services >=13 TB/s of reads into LDS on this
//   chip.  The cap is the vector-register load-return path, not the fabric.
// Fix: v2 geometry, but stream u and m through double-buffered LDS via
//   __builtin_amdgcn_global_load_lds (width=16, linear LDS dest = wave-uniform
//   base + lane*16 per the m104 contract, per-lane global source).  Wave w
//   stages channel s*8+w each step; compute = conflict-free ds_read_b128 +
//   12 FMA/thread; one barrier per step (compiler drains vmcnt there).

#define BB   32
#define CC   256
#define HWSZ 4096                 // H*W floats per plane
#define NPOS (BB * HWSZ)          // 131072 positions
#define HW4  (HWSZ / 4)           // 1024 float4 per plane
#define PPB  256                  // positions per block
#define NW   8                    // waves per block (512 threads)
#define NBLK (NPOS / PPB)         // 512 blocks (2/CU, whole grid co-resident)
#define NSTEP (CC / NW)           // 32 steps, channel = step*8 + wave
#define SIM_EPS 1e-8f

typedef float f32x4 __attribute__((ext_vector_type(4)));

// DMA 16 B/lane global->LDS.  LDS dest is wave-uniform; HW adds lane*16.
__device__ __forceinline__ void dma16(const f32x4* g, f32x4* lds)
{
    __builtin_amdgcn_global_load_lds(
        (const __attribute__((address_space(1))) void*)g,
        (__attribute__((address_space(3))) void*)lds,
        16, 0, 0);
}

__global__ __launch_bounds__(512) void
sim_dma_kernel(const f32x4* __restrict__ u4,
               const f32x4* __restrict__ m4,
               const int*   __restrict__ mask,
               double*      __restrict__ ws,
               float*       __restrict__ out)
{
    // Double-buffered stream tiles: [stage][wave][64 float4] = 16 KB x2.
    __shared__ f32x4 lds_u[2][NW][64];
    __shared__ f32x4 lds_m[2][NW][64];
    // Phase-2 per-wave partials (as in v2).
    __shared__ f32x4 s_num[NW][64];
    __shared__ f32x4 s_uu [NW][64];
    __shared__ f32x4 s_mm [NW][64];

    const int w = threadIdx.x >> 6;      // wave id = channel-sub (stride-8 comb)
    const int l = threadIdx.x & 63;      // lane = float4 position-group

    const int pos0  = blockIdx.x * PPB;
    const int b     = pos0 >> 12;        // pos0 / 4096 (PPB divides HWSZ)
    const int hw4_0 = (pos0 & (HWSZ - 1)) >> 2;

    // Prefetch mask (phase-2 input) so its load overlaps the main loop.
    int mk = 0;
    if (threadIdx.x < PPB) mk = mask[pos0 + threadIdx.x];

    // This lane's element within a channel plane; channel c adds c*HW4.
    const size_t lane_base = (size_t)b * CC * HW4 + (size_t)hw4_0 + (size_t)l;

    // Prologue: stage step 0 (channel = w) into buffer 0.
    dma16(u4 + lane_base + (size_t)w * HW4, &lds_u[0][w][0]);
    dma16(m4 + lane_base + (size_t)w * HW4, &lds_m[0][w][0]);
    __syncthreads();                     // drains vmcnt -> tile 0 resident

    f32x4 num = {0.f, 0.f, 0.f, 0.f};
    f32x4 uu  = {0.f, 0.f, 0.f, 0.f};
    f32x4 mm  = {0.f, 0.f, 0.f, 0.f};

#pragma unroll 2
    for (int s = 0; s < NSTEP; ++s) {
        const int cur = s & 1;
        // Issue next tile into the other buffer (block-uniform branch; all
        // 64 lanes of every wave execute the DMA -> full-exec contract holds).
        if (s + 1 < NSTEP) {
            const size_t c = (size_t)((s + 1) * NW + w);
            dma16(u4 + lane_base + c * HW4, &lds_u[cur ^ 1][w][0]);
            dma16(m4 + lane_base + c * HW4, &lds_m[cur ^ 1][w][0]);
        }
        // Compute current tile: 16 B/lane consecutive -> conflict-free b128.
        const f32x4 a  = lds_u[cur][w][l];
        const f32x4 bv = lds_m[cur][w][l];
        num[0] = fmaf(a[0], bv[0], num[0]);
        num[1] = fmaf(a[1], bv[1], num[1]);
        num[2] = fmaf(a[2], bv[2], num[2]);
        num[3] = fmaf(a[3], bv[3], num[3]);
        uu[0]  = fmaf(a[0], a[0],  uu[0]);
        uu[1]  = fmaf(a[1], a[1],  uu[1]);
        uu[2]  = fmaf(a[2], a[2],  uu[2]);
        uu[3]  = fmaf(a[3], a[3],  uu[3]);
        mm[0]  = fmaf(bv[0], bv[0], mm[0]);
        mm[1]  = fmaf(bv[1], bv[1], mm[1]);
        mm[2]  = fmaf(bv[2], bv[2], mm[2]);
        mm[3]  = fmaf(bv[3], bv[3], mm[3]);
        // Barrier: (a) next tile's DMA drained (compiler emits vmcnt(0) before
        // s_barrier), (b) everyone done reading buf[cur] before step s+2's
        // issue overwrites it.
        __syncthreads();
    }

    // Each thread now holds channel-comb {c : c%8==w} sums for its 4 positions.
    s_num[w][l] = num;
    s_uu [w][l] = uu;
    s_mm [w][l] = mm;
    __syncthreads();

    // Phase 2: first 4 waves combine the 8 channel-sub partials per position,
    // compute cosine sim, apply mask.
    double sd = 0.0, md = 0.0;
    if (threadIdx.x < PPB) {
        const int t = threadIdx.x;
        float fn = 0.f, fu = 0.f, fm = 0.f;
#pragma unroll
        for (int k = 0; k < NW; ++k) {
            fn += ((const float*)s_num[k])[t];
            fu += ((const float*)s_uu [k])[t];
            fm += ((const float*)s_mm [k])[t];
        }
        const float denom = fmaxf(sqrtf(fu), SIM_EPS) * fmaxf(sqrtf(fm), SIM_EPS);
        const float sim   = fn / denom;
        if (mk != 0) { sd = (double)sim; md = 1.0; }
    }

    // Block reduction: wave shfl (inactive waves contribute 0) -> LDS.
#pragma unroll
    for (int off = 32; off > 0; off >>= 1) {
        sd += __shfl_down(sd, off, 64);
        md += __shfl_down(md, off, 64);
    }

    __shared__ double r_s[NW];
    __shared__ double r_m[NW];
    if (l == 0) { r_s[w] = sd; r_m[w] = md; }
    __syncthreads();

    if (threadIdx.x == 0) {
        double ts = 0.0, tm = 0.0;
#pragma unroll
        for (int k = 0; k < NW; ++k) { ts += r_s[k]; tm += r_m[k]; }
        atomicAdd(&ws[0], ts);   // device-scope by default on CDNA
        atomicAdd(&ws[1], tm);
        __threadfence();         // make our adds visible before the ticket
        const unsigned long long prev =
            atomicAdd((unsigned long long*)&ws[2], 1ull);
        if (prev == (unsigned long long)(NBLK - 1)) {
            // Last block: every other block fenced its adds before the
            // ticket increment.  atomicAdd(+0.0) reads are device-coherent.
            const double s  = atomicAdd(&ws[0], 0.0);
            const double mc = atomicAdd(&ws[1], 0.0);
            out[0] = (float)(s / mc);
        }
    }
}

extern "C" void kernel_launch(void* const* d_in, const int* in_sizes, int n_in,
                              void* d_out, int out_size, void* d_ws, size_t ws_size,
                              hipStream_t stream)
{
    const f32x4* u4   = (const f32x4*)d_in[0];
    const f32x4* m4   = (const f32x4*)d_in[1];
    const int*   mask = (const int*)d_in[2];
    float*  out = (float*)d_out;
    double* ws  = (double*)d_ws;

    // ws is re-poisoned before every timed launch -> zero the two
    // accumulators + the completion ticket on-stream (graph-capture safe).
    hipMemsetAsync(d_ws, 0, 3 * sizeof(double), stream);

    sim_dma_kernel<<<NBLK, 512, 0, stream>>>(u4, m4, mask, ws, out);
}